// Round 7
// baseline (410.313 us; speedup 1.0000x reference)
//
#include <hip/hip_runtime.h>
#include <cstdint>
#include <cstddef>

#define B_   2
#define L_   4096
#define DM_  1024
#define DI_  2048
#define DT_  64
#define M_   (B_*L_)      // 8192 rows
#define G_   64           // scan chunks per row
#define CH_  (L_/G_)      // 64 elements per chunk
#define KSPL 8            // split-K factor for dt_low GEMM
#define KSL  (DI_/KSPL)   // 256 per split
#define BK_  32           // [128-tile path]
#define LDC  136          // C-stage LDS stride in bf16 (272B: 16B-aligned rows)
#define LDCF 68           // C-stage LDS stride in fp32 for EPI=4 (272B)

typedef __bf16 bf16;
typedef __bf16 bf16x8 __attribute__((ext_vector_type(8)));
typedef __bf16 bf16x4 __attribute__((ext_vector_type(4)));
typedef float  f32x4  __attribute__((ext_vector_type(4)));

__device__ __forceinline__ float silu_f(float x){ return x / (1.f + __expf(-x)); }
__device__ __forceinline__ float softplus_f(float x){
  return fmaxf(x, 0.f) + __logf(1.f + __expf(-fabsf(x)));
}
__device__ __forceinline__ float e_of(float delta, float Ad){
  float ee = __expf(delta * Ad);
  return fminf(fmaxf(ee, 1e-6f), 1.f);
}
__device__ __forceinline__ float a_of(const float* alog, int d){
  float Ad = -__expf(alog[d]);
  return fminf(fmaxf(Ad, -10.f), -1e-6f);
}

// async global->LDS, 16B per lane (m97). LDS dest = wave-uniform base + lane*16.
__device__ __forceinline__ void gl_lds16(const bf16* g, bf16* l){
  __builtin_amdgcn_global_load_lds(
      (const __attribute__((address_space(1))) void*)g,
      (__attribute__((address_space(3))) void*)l, 16, 0, 0);
}

// inline-asm ds_read_b128 (opaque to compiler waitcnt pass); caller places
// s_waitcnt lgkmcnt(N) + sched_barrier(0) per rule #18.
__device__ __forceinline__ void ds_read128(bf16x8& d, uint32_t addr){
  asm volatile("ds_read_b128 %0, %1" : "=v"(d) : "v"(addr));
}

// ---------------- fused fp32 -> bf16 conversion for all 5 weight/input tensors
__global__ __launch_bounds__(256)
void cvt_all_kernel(const float4* __restrict__ s0, bf16x4* __restrict__ d0, int n0,
                    const float4* __restrict__ s1, bf16x4* __restrict__ d1, int n1,
                    const float4* __restrict__ s2, bf16x4* __restrict__ d2, int n2,
                    const float4* __restrict__ s3, bf16x4* __restrict__ d3, int n3,
                    const float4* __restrict__ s4, bf16x4* __restrict__ d4, int n4)
{
  int i = blockIdx.x*256 + threadIdx.x;
  const float4* s; bf16x4* d;
  if      (i < n0)                 { s = s0; d = d0; }
  else if ((i -= n0) < n1)         { s = s1; d = d1; }
  else if ((i -= n1) < n2)         { s = s2; d = d2; }
  else if ((i -= n2) < n3)         { s = s3; d = d3; }
  else if ((i -= n3) < n4)         { s = s4; d = d4; }
  else return;
  float4 v = s[i];
  bf16x4 o = {(bf16)v.x, (bf16)v.y, (bf16)v.z, (bf16)v.w};
  d[i] = o;
}

// =====================================================================
// 256x(128*QN)-tile, BK=64, 8-wave (2Mx4N) GEMM — 8-phase schedule
// (T2+T3+T4+T5). C[M,N] = A[M,K] * W[N,K]^T, bf16 in.
// QN=2: 256x256 tile, per-wave 128x64, acc[8][4]  (GEMM1)
// QN=1: 256x128 tile, per-wave 128x32, acc[8][2]  (GEMM6: 256 blocks)
// OUT=0: bf16 split epilogue (n0<DI_ -> ob; n0>=DI_ -> silu -> ob2) [QN=2]
// OUT=3: fp32 plain epilogue -> of
// R6 post-mortem: GEMM1 profile showed uniform x0.65 scaling of ALL rate
// counters at identical work counters — throttled profile run suspected;
// GEMM1/GEMM6 code FROZEN this round for clean re-measurement (rule #13).
// Per K-tile, 4 phases (quadrants qm0qn0 / qm0qn1 / qm1qn1 / qm1qn0):
//   {ds_reads for this quadrant | stage chunks of tile t+1}
//   -> s_barrier -> lgkmcnt(0)+sched_barrier -> setprio(1) -> MFMA
//   -> setprio(0) -> [counted vmcnt] -> s_barrier     (never vmcnt(0) steady)
// QN=1 ledger: prologue 6 loads, vmcnt(2) leaves A1,A3; P0 stages B0',B1'
// (4 out); P1 stages A0' (5) -> vmcnt(3) drains A1,A3 of t; P2 stages
// A2',A1' (5); P3 stages A3' (6) -> vmcnt(2). Closed invariant.
// LDS swizzle: physical 16B chunk = logical ^ (row&7) on global source of
// gl_lds + on ds_read addr (both-sides involution). Measured 0 conflicts.
// =====================================================================
template<int OUT, int QN, int MT, int NT, int KT>
__global__ __launch_bounds__(512, 2)
void gemm256(const bf16* __restrict__ A, const bf16* __restrict__ W,
             bf16* __restrict__ ob, bf16* __restrict__ ob2,
             float* __restrict__ of)
{
  __shared__ __align__(16) char smem[131072];   // A: 2x32KiB | B: 2x(QN*16KiB)
  char* lA = smem;
  char* lB = smem + 65536;
  constexpr int BN = 128*QN;

  const int t    = threadIdx.x;
  const int lane = t & 63;
  const int wave = t >> 6;            // 0..7
  const int wm   = wave >> 2;         // 0..1  (M half)
  const int wn   = wave & 3;          // 0..3  (N quarter)
  const int l16  = lane & 15, quad = lane >> 4;

  // XCD-aware swizzle (nwg %8==0) then n-fast decomposition (A-stripe L2 reuse)
  const int nnt = NT / BN;
  const int nwg = (MT/256) * nnt;
  const int cpx = nwg >> 3;
  int lin = (blockIdx.x & 7) * cpx + (blockIdx.x >> 3);
  const int m0 = (lin / nnt) * 256;
  const int n0 = (lin % nnt) * BN;

  // ---- staging: chunk = 64 rows x 64 cols, 1 gl_lds per wave per chunk.
  const int r8     = lane >> 3;
  const int lchunk = (lane & 7) ^ r8;
  const bf16* ap[4]; const bf16* bp[2*QN];
  #pragma unroll
  for (int s = 0; s < 4; ++s)
    ap[s] = A + (size_t)(m0 + s*64 + wave*8 + r8) * KT + lchunk*8;
  #pragma unroll
  for (int s = 0; s < 2*QN; ++s)
    bp[s] = W + (size_t)(n0 + s*64 + wave*8 + r8) * KT + lchunk*8;

  // 32-bit LDS addresses for inline-asm ds_read
  const uint32_t lAu = (uint32_t)(uintptr_t)(__attribute__((address_space(3))) char*)lA;
  const uint32_t lBu = (uint32_t)(uintptr_t)(__attribute__((address_space(3))) char*)lB;
  const uint32_t swz0 = (uint32_t)(((quad    ) ^ (l16 & 7)) << 4);
  const uint32_t swz1 = (uint32_t)(((4 | quad) ^ (l16 & 7)) << 4);
  const uint32_t aB0 = lAu + (uint32_t)((wm*128 + l16) * 128) + swz0;  // ks0
  const uint32_t aB1 = lAu + (uint32_t)((wm*128 + l16) * 128) + swz1;  // ks1
  const uint32_t bB0 = lBu + (uint32_t)((wn*32*QN + l16) * 128) + swz0;
  const uint32_t bB1 = lBu + (uint32_t)((wn*32*QN + l16) * 128) + swz1;

  f32x4 acc[8][2*QN] = {};
  constexpr int NTILES = KT / 64;

  // ---- prologue: stage tile 0 (buf 0); last-issued = A1,A3 (needed at P2)
  #pragma unroll
  for (int s = 0; s < 2*QN; ++s){
    gl_lds16(bp[s], (bf16*)(lB + s*8192 + wave*1024)); bp[s] += 64;
  }
  gl_lds16(ap[0], (bf16*)(lA + 0*8192 + wave*1024)); ap[0] += 64;
  gl_lds16(ap[2], (bf16*)(lA + 2*8192 + wave*1024)); ap[2] += 64;
  gl_lds16(ap[1], (bf16*)(lA + 1*8192 + wave*1024)); ap[1] += 64;
  gl_lds16(ap[3], (bf16*)(lA + 3*8192 + wave*1024)); ap[3] += 64;
  asm volatile("s_waitcnt vmcnt(2)" ::: "memory");   // all but A1,A3 landed
  __builtin_amdgcn_s_barrier();

  for (int tt = 0; tt < NTILES; ++tt){
    const int u = tt & 1;
    const uint32_t ub = (uint32_t)(u << 15);
    char* sA = lA + (u^1)*32768;         // stage dest (other buffer)
    char* sB = lB + (u^1)*32768;
    const bool notlast = (tt + 1 < NTILES);

    // ======== P0: qm0 x qn0 ========
    bf16x8 a0k0[4], a0k1[4], b0k0[QN], b0k1[QN];
    #pragma unroll
    for (int mi = 0; mi < 4; ++mi) ds_read128(a0k0[mi], aB0 + ub + mi*2048);
    #pragma unroll
    for (int mi = 0; mi < 4; ++mi) ds_read128(a0k1[mi], aB1 + ub + mi*2048);
    #pragma unroll
    for (int ni = 0; ni < QN; ++ni) ds_read128(b0k0[ni], bB0 + ub + ni*2048);
    #pragma unroll
    for (int ni = 0; ni < QN; ++ni) ds_read128(b0k1[ni], bB1 + ub + ni*2048);
    if (notlast){
      gl_lds16(bp[0], (bf16*)(sB + 0*8192 + wave*1024)); bp[0] += 64;
      gl_lds16(bp[1], (bf16*)(sB + 1*8192 + wave*1024)); bp[1] += 64;
    }
    if (QN == 2) asm volatile("s_waitcnt lgkmcnt(8)" ::: "memory");  // 12-read phase
    __builtin_amdgcn_s_barrier();
    asm volatile("s_waitcnt lgkmcnt(0)" ::: "memory");
    __builtin_amdgcn_sched_barrier(0);
    __builtin_amdgcn_s_setprio(1);
    #pragma unroll
    for (int mi = 0; mi < 4; ++mi)
      #pragma unroll
      for (int ni = 0; ni < QN; ++ni)
        acc[mi][ni] = __builtin_amdgcn_mfma_f32_16x16x32_bf16(a0k0[mi], b0k0[ni], acc[mi][ni], 0, 0, 0);
    #pragma unroll
    for (int mi = 0; mi < 4; ++mi)
      #pragma unroll
      for (int ni = 0; ni < QN; ++ni)
        acc[mi][ni] = __builtin_amdgcn_mfma_f32_16x16x32_bf16(a0k1[mi], b0k1[ni], acc[mi][ni], 0, 0, 0);
    __builtin_amdgcn_s_setprio(0);
    __builtin_amdgcn_sched_barrier(0);
    __builtin_amdgcn_s_barrier();

    // ======== P1: qm0 x qn1 ========
    bf16x8 b1k0[QN], b1k1[QN];
    #pragma unroll
    for (int ni = 0; ni < QN; ++ni) ds_read128(b1k0[ni], bB0 + ub + (QN+ni)*2048);
    #pragma unroll
    for (int ni = 0; ni < QN; ++ni) ds_read128(b1k1[ni], bB1 + ub + (QN+ni)*2048);
    if (notlast){
      if (QN == 2){
        gl_lds16(bp[2], (bf16*)(sB + 2*8192 + wave*1024)); bp[2] += 64;
        gl_lds16(bp[3], (bf16*)(sB + 3*8192 + wave*1024)); bp[3] += 64;
      } else {
        gl_lds16(ap[0], (bf16*)(sA + 0*8192 + wave*1024)); ap[0] += 64;
      }
    }
    __builtin_amdgcn_s_barrier();
    asm volatile("s_waitcnt lgkmcnt(0)" ::: "memory");
    __builtin_amdgcn_sched_barrier(0);
    __builtin_amdgcn_s_setprio(1);
    #pragma unroll
    for (int mi = 0; mi < 4; ++mi)
      #pragma unroll
      for (int ni = 0; ni < QN; ++ni)
        acc[mi][QN+ni] = __builtin_amdgcn_mfma_f32_16x16x32_bf16(a0k0[mi], b1k0[ni], acc[mi][QN+ni], 0, 0, 0);
    #pragma unroll
    for (int mi = 0; mi < 4; ++mi)
      #pragma unroll
      for (int ni = 0; ni < QN; ++ni)
        acc[mi][QN+ni] = __builtin_amdgcn_mfma_f32_16x16x32_bf16(a0k1[mi], b1k1[ni], acc[mi][QN+ni], 0, 0, 0);
    __builtin_amdgcn_s_setprio(0);
    __builtin_amdgcn_sched_barrier(0);
    if (notlast){
      if (QN == 2) asm volatile("s_waitcnt vmcnt(4)" ::: "memory");  // A1,A3 of t landed
      else         asm volatile("s_waitcnt vmcnt(3)" ::: "memory");
    } else {
      asm volatile("s_waitcnt vmcnt(0)" ::: "memory");
    }
    __builtin_amdgcn_s_barrier();

    // ======== P2: qm1 x qn1 ========
    bf16x8 a1k0[4], a1k1[4];
    #pragma unroll
    for (int mi = 0; mi < 4; ++mi) ds_read128(a1k0[mi], aB0 + ub + (4+mi)*2048);
    #pragma unroll
    for (int mi = 0; mi < 4; ++mi) ds_read128(a1k1[mi], aB1 + ub + (4+mi)*2048);
    if (notlast){
      if (QN == 2){
        gl_lds16(ap[0], (bf16*)(sA + 0*8192 + wave*1024)); ap[0] += 64;
        gl_lds16(ap[2], (bf16*)(sA + 2*8192 + wave*1024)); ap[2] += 64;
      } else {
        gl_lds16(ap[2], (bf16*)(sA + 2*8192 + wave*1024)); ap[2] += 64;
        gl_lds16(ap[1], (bf16*)(sA + 1*8192 + wave*1024)); ap[1] += 64;
      }
    }
    __builtin_amdgcn_s_barrier();
    asm volatile("s_waitcnt lgkmcnt(0)" ::: "memory");
    __builtin_amdgcn_sched_barrier(0);
    __builtin_amdgcn_s_setprio(1);
    #pragma unroll
    for (int mi = 0; mi < 4; ++mi)
      #pragma unroll
      for (int ni = 0; ni < QN; ++ni)
        acc[4+mi][QN+ni] = __builtin_amdgcn_mfma_f32_16x16x32_bf16(a1k0[mi], b1k0[ni], acc[4+mi][QN+ni], 0, 0, 0);
    #pragma unroll
    for (int mi = 0; mi < 4; ++mi)
      #pragma unroll
      for (int ni = 0; ni < QN; ++ni)
        acc[4+mi][QN+ni] = __builtin_amdgcn_mfma_f32_16x16x32_bf16(a1k1[mi], b1k1[ni], acc[4+mi][QN+ni], 0, 0, 0);
    __builtin_amdgcn_s_setprio(0);
    __builtin_amdgcn_sched_barrier(0);
    __builtin_amdgcn_s_barrier();

    // ======== P3: qm1 x qn0 (0 reads; a1*, b0* live) ========
    if (notlast){
      if (QN == 2){
        gl_lds16(ap[1], (bf16*)(sA + 1*8192 + wave*1024)); ap[1] += 64;
        gl_lds16(ap[3], (bf16*)(sA + 3*8192 + wave*1024)); ap[3] += 64;
      } else {
        gl_lds16(ap[3], (bf16*)(sA + 3*8192 + wave*1024)); ap[3] += 64;
      }
    }
    __builtin_amdgcn_s_barrier();
    __builtin_amdgcn_sched_barrier(0);
    __builtin_amdgcn_s_setprio(1);
    #pragma unroll
    for (int mi = 0; mi < 4; ++mi)
      #pragma unroll
      for (int ni = 0; ni < QN; ++ni)
        acc[4+mi][ni] = __builtin_amdgcn_mfma_f32_16x16x32_bf16(a1k0[mi], b0k0[ni], acc[4+mi][ni], 0, 0, 0);
    #pragma unroll
    for (int mi = 0; mi < 4; ++mi)
      #pragma unroll
      for (int ni = 0; ni < QN; ++ni)
        acc[4+mi][ni] = __builtin_amdgcn_mfma_f32_16x16x32_bf16(a1k1[mi], b0k1[ni], acc[4+mi][ni], 0, 0, 0);
    __builtin_amdgcn_s_setprio(0);
    __builtin_amdgcn_sched_barrier(0);
    if (notlast) asm volatile("s_waitcnt vmcnt(2)" ::: "memory");  // next tile's P0 data landed
    __builtin_amdgcn_s_barrier();
  }

  // ---- epilogue. acc C/D layout: col = lane&15, row = quad*4 + reg
  if (OUT == 3){
    // fp32 full tile via 4 passes of 64 rows through LDS
    constexpr int LDE = 128*QN + 4;        // f32 stride, 16B-aligned
    float* Cf = (float*)smem;
    #pragma unroll
    for (int pass = 0; pass < 4; ++pass){
      if (wm == (pass >> 1)){
        #pragma unroll
        for (int mi2 = 0; mi2 < 4; ++mi2){
          const int mi = (pass & 1)*4 + mi2;
          #pragma unroll
          for (int ni = 0; ni < 2*QN; ++ni)
            #pragma unroll
            for (int r = 0; r < 4; ++r)
              Cf[(mi2*16 + quad*4 + r)*LDE + wn*32*QN + ni*16 + l16] = acc[mi][ni][r];
        }
      }
      __syncthreads();
      constexpr int f4row = 32*QN;         // float4 per row
      constexpr int rpi   = 512/f4row;     // rows per iter
      #pragma unroll
      for (int it = 0; it < 64/rpi; ++it){
        const int row = it*rpi + (t / f4row);
        const int c4  = (t % f4row) * 4;
        float4 v = *(const float4*)&Cf[row*LDE + c4];
        *(float4*)&of[(size_t)(m0 + pass*64 + row)*NT + n0 + c4] = v;
      }
      __syncthreads();
    }
  } else {
    // bf16 split epilogue: 2 passes of 128 rows (QN=2 only; stride 264 bf16)
    bf16* Cs = (bf16*)smem;
    const bool isg  = (n0 >= DI_);
    bf16* outp      = isg ? ob2 : ob;
    const int ncol0 = isg ? (n0 - DI_) : n0;
    #pragma unroll
    for (int pass = 0; pass < 2; ++pass){
      if (wm == pass){
        #pragma unroll
        for (int mi = 0; mi < 8; ++mi)
          #pragma unroll
          for (int ni = 0; ni < 2*QN; ++ni)
            #pragma unroll
            for (int r = 0; r < 4; ++r){
              float v = acc[mi][ni][r];
              if (isg) v = silu_f(v);
              Cs[(mi*16 + quad*4 + r)*264 + wn*32*QN + ni*16 + l16] = (bf16)v;
            }
      }
      __syncthreads();
      #pragma unroll
      for (int it = 0; it < 8; ++it){
        const int row = it*16 + (t >> 5);
        const int c8  = (t & 31) * 8;
        bf16x8 v = *(const bf16x8*)&Cs[row*264 + c8];
        *(bf16x8*)&outp[(size_t)(m0 + pass*128 + row)*DI_ + ncol0 + c8] = v;
      }
      __syncthreads();
    }
  }
}

// ---------------- GEMM: C[M,N] = A[M,K] * W[N,K]^T, bf16 MFMA ----------------
// m97 K-loop, 128-tile path for the small/odd-shape GEMMs.
// EPI: 2 = dt epilogue (softplus/clip -> delta bf16) + FUSED scan pass1
//      4 = split-K partial fp32 (dt_low, N=64), K-slice from blockIdx.z
template<int EPI, int MT, int NT, int KT>
__global__ __launch_bounds__(256)
void gemm_bt(const bf16* __restrict__ A, const bf16* __restrict__ W,
             float* __restrict__ o0, bf16* __restrict__ ob, bf16* __restrict__ ob2,
             const float* __restrict__ bias, const float* __restrict__ alog,
             const bf16* __restrict__ uq, float* __restrict__ Pq,
             float* __restrict__ Fq)
{
  __shared__ char smem[34816];                 // As/Bs (16 KiB) reused as C-stage
  bf16* As = (bf16*)smem;
  bf16* Bs = (bf16*)(smem + 128*BK_*2);
  const int t    = threadIdx.x;
  const int lane = t & 63;
  const int wave = t >> 6;
  const int wm   = wave >> 1, wn = wave & 1;
  const int l16  = lane & 15, quad = lane >> 4;

  int m0, n0;
  if (EPI == 4){
    m0 = blockIdx.y * 128; n0 = 0;
  } else {
    const int gx  = NT / 128;
    const int lin = blockIdx.y * gx + blockIdx.x;
    const int grp = lin / (gx * 4);
    const int rem = lin % (gx * 4);
    m0 = (grp * 4 + (rem & 3)) * 128;
    n0 = (rem >> 2) * 128;
  }

  const int srow = (lane >> 2);
  const int scol = (lane & 3) * 8;

  const int KFULL = (EPI == 4) ? (KT * KSPL) : KT;
  const int kbase = (EPI == 4) ? (int)blockIdx.z * KT : 0;

  const int rowA0 = m0 + wave*32 + srow;
  int rB0 = n0 + wave*32 + srow, rB1 = rB0 + 16;
  if (NT < 128){ rB0 = (rB0 >= NT) ? NT-1 : rB0; rB1 = (rB1 >= NT) ? NT-1 : rB1; }
  const bf16* ap0 = A + (size_t)rowA0*KFULL        + kbase + scol;
  const bf16* ap1 = A + (size_t)(rowA0+16)*KFULL   + kbase + scol;
  const bf16* bp0 = W + (size_t)rB0*KFULL          + kbase + scol;
  const bf16* bp1 = W + (size_t)rB1*KFULL          + kbase + scol;
  bf16* lA0 = &As[(wave*32)*BK_];
  bf16* lA1 = &As[(wave*32+16)*BK_];
  bf16* lB0 = &Bs[(wave*32)*BK_];
  bf16* lB1 = &Bs[(wave*32+16)*BK_];

  f32x4 acc[4][4] = {};
  constexpr int kframes = KT / BK_;

  for (int kt = 0; kt < kframes; ++kt){
    gl_lds16(ap0, lA0);  gl_lds16(ap1, lA1);
    gl_lds16(bp0, lB0);  gl_lds16(bp1, lB1);
    ap0 += BK_; ap1 += BK_; bp0 += BK_; bp1 += BK_;
    __syncthreads();
    bf16x8 af[4], bf_[4];
    #pragma unroll
    for (int i = 0; i < 4; ++i){
      af[i]  = *(const bf16x8*)&As[(wm*64 + i*16 + l16)*BK_ + quad*8];
      bf_[i] = *(const bf16x8*)&Bs[(wn*64 + i*16 + l16)*BK_ + quad*8];
    }
    #pragma unroll
    for (int mi = 0; mi < 4; ++mi)
      #pragma unroll
      for (int ni = 0; ni < 4; ++ni)
        acc[mi][ni] = __builtin_amdgcn_mfma_f32_16x16x32_bf16(af[mi], bf_[ni], acc[mi][ni], 0, 0, 0);
    __syncthreads();
  }

  if (EPI == 4){
    float* Cf = (float*)smem;
    if (wn == 0){
      #pragma unroll
      for (int mi = 0; mi < 4; ++mi)
        #pragma unroll
        for (int ni = 0; ni < 4; ++ni)
          #pragma unroll
          for (int r = 0; r < 4; ++r)
            Cf[(wm*64 + mi*16 + quad*4 + r)*LDCF + ni*16 + l16] = acc[mi][ni][r];
    }
    __syncthreads();
    #pragma unroll
    for (int it = 0; it < 8; ++it){
      const int row = it*16 + (t >> 4);
      const int c4  = (t & 15) * 4;
      float4 v = *(const float4*)&Cf[row*LDCF + c4];
      *(float4*)&o0[((size_t)blockIdx.z*M_ + m0 + row)*DT_ + c4] = v;
    }
  } else {
    // bf16 outputs (EPI 2) via padded LDS stage
    bf16* Cs = (bf16*)smem;
    #pragma unroll
    for (int mi = 0; mi < 4; ++mi){
      #pragma unroll
      for (int ni = 0; ni < 4; ++ni){
        const int n = n0 + wn*64 + ni*16 + l16;
        #pragma unroll
        for (int r = 0; r < 4; ++r){
          float v = acc[mi][ni][r];
          v = softplus_f(v + bias[n]);
          v = fminf(fmaxf(v, 1e-6f), 10.f);      // delta
          Cs[(wm*64 + mi*16 + quad*4 + r)*LDC + wn*64 + ni*16 + l16] = (bf16)v;
        }
      }
    }
    __syncthreads();
    #pragma unroll
    for (int it = 0; it < 8; ++it){
      const int row = it*16 + (t >> 4);
      const int c8  = (t & 15) * 8;
      bf16x8 v = *(const bf16x8*)&Cs[row*LDC + c8];
      *(bf16x8*)&ob[(size_t)(m0+row)*NT + n0 + c8] = v;
    }
    {
      // fused scan pass1 (bit-identical to standalone: uses bf16 delta in LDS)
      const int chunk = t >> 7;
      const int dcol  = t & 127;
      const int dglob = n0 + dcol;
      const float Ad  = a_of(alog, dglob);
      const int b  = m0 >> 12;
      const int c0 = (m0 & 4095) >> 6;
      const size_t ubase = (size_t)(m0 + chunk*64)*DI_ + dglob;
      float p = 1.f, f = 0.f;
      for (int i = 0; i < CH_; ++i){
        float dl = (float)Cs[(chunk*64 + i)*LDC + dcol];
        float ee = e_of(dl, Ad);
        float uu = (float)uq[ubase + (size_t)i*DI_];
        f = f*ee + uu;
        p *= ee;
      }
      const size_t o = ((size_t)(b*G_ + c0 + chunk))*DI_ + dglob;
      Pq[o] = p; Fq[o] = f;
    }
  }
}

// ---------------- split-K reduce: dtl = sum_z partial[z] (bf16) ----------------
// R7: vectorized — float4 loads (16 B/lane), 4 outputs/thread, bf16x4 store.
__global__ __launch_bounds__(256)
void dt_reduce_kernel(const float* __restrict__ part, bf16* __restrict__ dtl){
  const int i = (blockIdx.x*256 + threadIdx.x) * 4;   // m*DT + n, x4
  float4 s = *(const float4*)&part[i];
  #pragma unroll
  for (int z = 1; z < KSPL; ++z){
    float4 v = *(const float4*)&part[(size_t)z*M_*DT_ + i];
    s.x += v.x; s.y += v.y; s.z += v.z; s.w += v.w;
  }
  bf16x4 o = {(bf16)s.x, (bf16)s.y, (bf16)s.z, (bf16)s.w};
  *(bf16x4*)&dtl[i] = o;
}

// ---------------- depthwise causal conv (K=4) + bias + SiLU ----------------
// Vectorized bf16x8 (G13) — one block = one (b,l) row, lane owns 8 d's;
// the l-boundary branch is block-uniform. 4x 16B loads + 1x 16B store.
__global__ __launch_bounds__(256)
void conv_silu_kernel(const bf16* __restrict__ xi, const float* __restrict__ cw,
                      const float* __restrict__ cb, bf16* __restrict__ ubf)
{
  const int row = blockIdx.x;               // b*L + l
  const int l   = row & (L_-1);
  const int d0  = threadIdx.x * 8;
  const size_t base = (size_t)row*DI_ + d0;
  float s[8];
  #pragma unroll
  for (int j = 0; j < 8; ++j) s[j] = cb[d0+j];
  float w[8][4];
  #pragma unroll
  for (int j = 0; j < 8; ++j){
    float4 wv = *(const float4*)&cw[(d0+j)*4];
    w[j][0] = wv.x; w[j][1] = wv.y; w[j][2] = wv.z; w[j][3] = wv.w;
  }
  #pragma unroll
  for (int k = 0; k < 4; ++k){
    const int ll = l + k - 3;
    if (ll >= 0){
      bf16x8 xv = *(const bf16x8*)&xi[base + (ptrdiff_t)(k-3)*DI_];
      #pragma unroll
      for (int j = 0; j < 8; ++j) s[j] += (float)xv[j] * w[j][k];
    }
  }
  bf16x8 o;
  #pragma unroll
  for (int j = 0; j < 8; ++j) o[j] = (bf16)silu_f(s[j]);
  *(bf16x8*)&ubf[base] = o;
}

// ---------------- scan pass3 (with inlined pass2 prefix) ----------------
// R7: vectorized (G13) — 4 d's per thread: bf16x4 (8 B/lane) on delta/u/g/y,
// float4 on the P/F prefix loads. Grid (DI/1024, G, B) = 256 blocks.
__global__ __launch_bounds__(256)
void scan_pass3(const bf16* __restrict__ delta, const bf16* __restrict__ u,
                const bf16* __restrict__ g, const float* __restrict__ P,
                const float* __restrict__ F, const float* __restrict__ alog,
                const float* __restrict__ Dp, bf16* __restrict__ y)
{
  const int d0 = (blockIdx.x*256 + threadIdx.x) * 4;
  const int c = blockIdx.y, b = blockIdx.z;
  float Ad[4], s[4], Dd[4];
  #pragma unroll
  for (int j = 0; j < 4; ++j){
    Ad[j] = a_of(alog, d0+j);
    Dd[j] = Dp[d0+j];
    s[j]  = 0.f;
  }
  for (int cc = 0; cc < c; ++cc){
    const size_t o = ((size_t)(b*G_ + cc))*DI_ + d0;
    float4 Fv = *(const float4*)&F[o];
    float4 Pv = *(const float4*)&P[o];
    s[0] = Fv.x + Pv.x*s[0];
    s[1] = Fv.y + Pv.y*s[1];
    s[2] = Fv.z + Pv.z*s[2];
    s[3] = Fv.w + Pv.w*s[3];
  }
  size_t base = ((size_t)(b*L_ + c*CH_))*DI_ + d0;
  for (int i = 0; i < CH_; ++i){
    const size_t idx = base + (size_t)i*DI_;
    bf16x4 dv = *(const bf16x4*)&delta[idx];
    bf16x4 uv = *(const bf16x4*)&u[idx];
    bf16x4 gv = *(const bf16x4*)&g[idx];
    bf16x4 yv;
    #pragma unroll
    for (int j = 0; j < 4; ++j){
      const float uu = (float)uv[j];
      s[j] = s[j]*e_of((float)dv[j], Ad[j]) + uu;
      float yy = s[j] + uu*Dd[j];
      yy = fminf(fmaxf(yy, -1e4f), 1e4f);
      yy *= (float)gv[j];             // g = silu(z), from GEMM1 epilogue
      yv[j] = (bf16)yy;
    }
    *(bf16x4*)&y[idx] = yv;
  }
}

// ---------------- host launch ----------------
extern "C" void kernel_launch(void* const* d_in, const int* in_sizes, int n_in,
                              void* d_out, int out_size, void* d_ws, size_t ws_size,
                              hipStream_t stream)
{
  (void)in_sizes; (void)n_in; (void)out_size; (void)ws_size;
  const float* x        = (const float*)d_in[0];
  const float* in_w     = (const float*)d_in[1];
  const float* conv_w   = (const float*)d_in[2];
  const float* conv_b   = (const float*)d_in[3];
  const float* xproj_w  = (const float*)d_in[4];
  const float* dtproj_w = (const float*)d_in[5];
  const float* dtproj_b = (const float*)d_in[6];
  const float* A_log    = (const float*)d_in[7];
  const float* Dp       = (const float*)d_in[8];
  const float* out_w    = (const float*)d_in[9];

  char* base = (char*)d_ws;
  const size_t MiB = 1024*1024;
  bf16*  xi_bf = (bf16*) (base + 0);
  float* part  = (float*)(base + 0);          // 16 MiB
  bf16*  dl_bf = (bf16*) (base + 0);          // delta, 32 MiB
  bf16*  x_bf  = (bf16*) (base + 32*MiB);     // 16 MiB
  bf16*  w1_bf = (bf16*) (base + 48*MiB);     // 8 MiB
  bf16*  g_bf  = (bf16*) (base + 64*MiB);     // 32 MiB
  bf16*  u_bf  = (bf16*) (base + 96*MiB);     // 32 MiB
  bf16*  y_bf  = (bf16*) (base + 128*MiB);    // 32 MiB
  bf16*  wo_bf = (bf16*) (base + 160*MiB);    // 4 MiB
  bf16*  xp_bf = (bf16*) (base + 164*MiB);    // 0.25 MiB
  bf16*  dp_bf = (bf16*) (base + 165*MiB);    // 0.25 MiB
  bf16*  dtl_bf= (bf16*) (base + 166*MiB);    // 1 MiB
  float* P     = (float*)(base + 167*MiB);    // 1 MiB
  float* F     = (float*)(base + 168*MiB);    // 1 MiB

  const int c0 = (M_*DM_)/4, c1 = (2*DI_*DM_)/4, c2 = (DT_*DI_)/4,
            c3 = (DI_*DT_)/4, c4 = (DM_*DI_)/4;
  const int ctot = c0+c1+c2+c3+c4;
  cvt_all_kernel<<<(ctot+255)/256, 256, 0, stream>>>(
      (const float4*)x,        (bf16x4*)x_bf,  c0,
      (const float4*)in_w,     (bf16x4*)w1_bf, c1,
      (const float4*)xproj_w,  (bf16x4*)xp_bf, c2,
      (const float4*)dtproj_w, (bf16x4*)dp_bf, c3,
      (const float4*)out_w,    (bf16x4*)wo_bf, c4);

  // 1) xz = x @ in_proj_w^T ; split -> xi (bf16), g=silu(z) (bf16)
  gemm256<0, 2, M_, 2*DI_, DM_><<<dim3((M_/256)*((2*DI_)/256)), 512, 0, stream>>>(
      x_bf, w1_bf, xi_bf, g_bf, nullptr);
  // 2) depthwise causal conv + bias + silu -> u (bf16); 1 block per (b,l) row
  conv_silu_kernel<<<M_, 256, 0, stream>>>(xi_bf, conv_w, conv_b, u_bf);
  // 3) dt_low = u @ x_proj_w^T, split-K=8 -> fp32 partials
  gemm_bt<4, M_, DT_, KSL><<<dim3(1, M_/128, KSPL), 256, 0, stream>>>(
      u_bf, xp_bf, part, nullptr, nullptr, nullptr,
      nullptr, nullptr, nullptr, nullptr);
  dt_reduce_kernel<<<(M_*DT_)/1024, 256, 0, stream>>>(part, dtl_bf);
  // 4) delta = clip(softplus(dtl @ dt_proj_w^T + b)) -> bf16 + fused scan pass1
  gemm_bt<2, M_, DI_, DT_><<<dim3(DI_/128, M_/128), 256, 0, stream>>>(
      dtl_bf, dp_bf, nullptr, dl_bf, nullptr, dtproj_b,
      A_log, u_bf, P, F);
  // 5) scan: prefix from P,F + within-chunk states + skip + gate -> y (bf16)
  //    vectorized 4 d/thread: grid (2, 64, 2) = 256 blocks
  scan_pass3<<<dim3(DI_/1024, G_, B_), 256, 0, stream>>>(
      dl_bf, u_bf, g_bf, P, F, A_log, Dp, y_bf);
  // 6) out = y @ out_proj_w^T (fp32) — QN=1 tile (256x128): grid 32*8=256
  gemm256<3, 1, M_, DM_, DI_><<<dim3((M_/256)*(DM_/128)), 512, 0, stream>>>(
      y_bf, wo_bf, nullptr, nullptr, (float*)d_out);
}

// Round 8
// 377.288 us; speedup vs baseline: 1.0875x; 1.0875x over previous
//
#include <hip/hip_runtime.h>
#include <cstdint>
#include <cstddef>

#define B_   2
#define L_   4096
#define DM_  1024
#define DI_  2048
#define DT_  64
#define M_   (B_*L_)      // 8192 rows
#define G_   64           // scan chunks per row
#define CH_  (L_/G_)      // 64 elements per chunk
#define KSPL 8            // split-K factor for dt_low GEMM
#define KSL  (DI_/KSPL)   // 256 per split
#define BK_  32           // [128-tile path]
#define LDC  136          // C-stage LDS stride in bf16 (272B: 16B-aligned rows)
#define LDCF 68           // C-stage LDS stride in fp32 for EPI=4 (272B)

typedef __bf16 bf16;
typedef __bf16 bf16x8 __attribute__((ext_vector_type(8)));
typedef __bf16 bf16x4 __attribute__((ext_vector_type(4)));
typedef float  f32x4  __attribute__((ext_vector_type(4)));

__device__ __forceinline__ float silu_f(float x){ return x / (1.f + __expf(-x)); }
__device__ __forceinline__ float softplus_f(float x){
  return fmaxf(x, 0.f) + __logf(1.f + __expf(-fabsf(x)));
}
__device__ __forceinline__ float e_of(float delta, float Ad){
  float ee = __expf(delta * Ad);
  return fminf(fmaxf(ee, 1e-6f), 1.f);
}
__device__ __forceinline__ float a_of(const float* alog, int d){
  float Ad = -__expf(alog[d]);
  return fminf(fmaxf(Ad, -10.f), -1e-6f);
}

// async global->LDS, 16B per lane (m97). LDS dest = wave-uniform base + lane*16.
__device__ __forceinline__ void gl_lds16(const bf16* g, bf16* l){
  __builtin_amdgcn_global_load_lds(
      (const __attribute__((address_space(1))) void*)g,
      (__attribute__((address_space(3))) void*)l, 16, 0, 0);
}

// inline-asm ds_read_b128 (opaque to compiler waitcnt pass); caller places
// s_waitcnt lgkmcnt(N) + sched_barrier(0) per rule #18.
__device__ __forceinline__ void ds_read128(bf16x8& d, uint32_t addr){
  asm volatile("ds_read_b128 %0, %1" : "=v"(d) : "v"(addr));
}

// ---------------- fused fp32 -> bf16 conversion for all 5 weight/input tensors
__global__ __launch_bounds__(256)
void cvt_all_kernel(const float4* __restrict__ s0, bf16x4* __restrict__ d0, int n0,
                    const float4* __restrict__ s1, bf16x4* __restrict__ d1, int n1,
                    const float4* __restrict__ s2, bf16x4* __restrict__ d2, int n2,
                    const float4* __restrict__ s3, bf16x4* __restrict__ d3, int n3,
                    const float4* __restrict__ s4, bf16x4* __restrict__ d4, int n4)
{
  int i = blockIdx.x*256 + threadIdx.x;
  const float4* s; bf16x4* d;
  if      (i < n0)                 { s = s0; d = d0; }
  else if ((i -= n0) < n1)         { s = s1; d = d1; }
  else if ((i -= n1) < n2)         { s = s2; d = d2; }
  else if ((i -= n2) < n3)         { s = s3; d = d3; }
  else if ((i -= n3) < n4)         { s = s4; d = d4; }
  else return;
  float4 v = s[i];
  bf16x4 o = {(bf16)v.x, (bf16)v.y, (bf16)v.z, (bf16)v.w};
  d[i] = o;
}

// =====================================================================
// GEMM1: xz = x @ in_proj_w^T. 256x256 tile, BK=64, 8-wave (2Mx4N),
// 8-phase schedule (T2+T3+T4+T5). STANDALONE (R8): de-templated — R6/R7's
// co-compiled QN=1 sibling perturbed this kernel's codegen (VGPR 120->116,
// dur 97->150 µs across two profile runs; rule #19). Body is R4's verbatim.
// bf16 split epilogue: n0<DI_ -> ob (xi); n0>=DI_ -> silu -> ob2 (g).
// Per K-tile, 4 phases (qm0qn0/qm0qn1/qm1qn1/qm1qn0):
//   {ds_reads for this quadrant (12/4/8/0) | stage 2 chunks of tile t+1}
//   -> s_barrier -> lgkmcnt(0)+sched_barrier -> setprio(1) -> 16 MFMA
//   -> setprio(0) -> [counted vmcnt 4/2] -> s_barrier  (never 0 steady)
// LDS swizzle: physical 16B chunk = logical ^ (row&7) on global source +
// ds_read addr (both-sides involution). Measured 0 bank conflicts.
// =====================================================================
__global__ __launch_bounds__(512, 2)
void gemm256_xz(const bf16* __restrict__ A, const bf16* __restrict__ W,
                bf16* __restrict__ ob, bf16* __restrict__ ob2)
{
  constexpr int MT = M_;       // 8192
  constexpr int NT = 2*DI_;    // 4096
  constexpr int KT = DM_;      // 1024
  __shared__ __align__(16) char smem[131072];   // A: 2x32KiB | B: 2x32KiB
  char* lA = smem;
  char* lB = smem + 65536;

  const int t    = threadIdx.x;
  const int lane = t & 63;
  const int wave = t >> 6;            // 0..7
  const int wm   = wave >> 2;         // 0..1  (M half)
  const int wn   = wave & 3;          // 0..3  (N quarter)
  const int l16  = lane & 15, quad = lane >> 4;

  // XCD-aware swizzle (nwg %8==0) then n-fast decomposition (A-stripe L2 reuse)
  const int nnt = NT / 256;
  const int nwg = (MT/256) * nnt;
  const int cpx = nwg >> 3;
  int lin = (blockIdx.x & 7) * cpx + (blockIdx.x >> 3);
  const int m0 = (lin / nnt) * 256;
  const int n0 = (lin % nnt) * 256;

  // ---- staging: chunk = 64 rows x 64 cols, 1 gl_lds per wave per chunk.
  const int r8     = lane >> 3;
  const int lchunk = (lane & 7) ^ r8;
  const bf16* ap[4]; const bf16* bp[4];
  #pragma unroll
  for (int s = 0; s < 4; ++s){
    ap[s] = A + (size_t)(m0 + s*64 + wave*8 + r8) * KT + lchunk*8;
    bp[s] = W + (size_t)(n0 + s*64 + wave*8 + r8) * KT + lchunk*8;
  }

  // 32-bit LDS addresses for inline-asm ds_read
  const uint32_t lAu = (uint32_t)(uintptr_t)(__attribute__((address_space(3))) char*)lA;
  const uint32_t lBu = (uint32_t)(uintptr_t)(__attribute__((address_space(3))) char*)lB;
  const uint32_t swz0 = (uint32_t)(((quad    ) ^ (l16 & 7)) << 4);
  const uint32_t swz1 = (uint32_t)(((4 | quad) ^ (l16 & 7)) << 4);
  const uint32_t aB0 = lAu + (uint32_t)((wm*128 + l16) * 128) + swz0;  // ks0
  const uint32_t aB1 = lAu + (uint32_t)((wm*128 + l16) * 128) + swz1;  // ks1
  const uint32_t bB0 = lBu + (uint32_t)((wn*64  + l16) * 128) + swz0;
  const uint32_t bB1 = lBu + (uint32_t)((wn*64  + l16) * 128) + swz1;

  f32x4 acc[8][4] = {};
  constexpr int NTILES = KT / 64;

  // ---- prologue: stage tile 0 (buf 0); last-issued = A1,A3 (needed at P2)
  gl_lds16(bp[0], (bf16*)(lB + 0*8192 + wave*1024)); bp[0] += 64;
  gl_lds16(bp[1], (bf16*)(lB + 1*8192 + wave*1024)); bp[1] += 64;
  gl_lds16(bp[2], (bf16*)(lB + 2*8192 + wave*1024)); bp[2] += 64;
  gl_lds16(bp[3], (bf16*)(lB + 3*8192 + wave*1024)); bp[3] += 64;
  gl_lds16(ap[0], (bf16*)(lA + 0*8192 + wave*1024)); ap[0] += 64;
  gl_lds16(ap[2], (bf16*)(lA + 2*8192 + wave*1024)); ap[2] += 64;
  gl_lds16(ap[1], (bf16*)(lA + 1*8192 + wave*1024)); ap[1] += 64;
  gl_lds16(ap[3], (bf16*)(lA + 3*8192 + wave*1024)); ap[3] += 64;
  asm volatile("s_waitcnt vmcnt(2)" ::: "memory");   // all but A1,A3 landed
  __builtin_amdgcn_s_barrier();

  for (int tt = 0; tt < NTILES; ++tt){
    const int u = tt & 1;
    const uint32_t ub = (uint32_t)(u << 15);
    char* sA = lA + (u^1)*32768;         // stage dest (other buffer)
    char* sB = lB + (u^1)*32768;
    const bool notlast = (tt + 1 < NTILES);

    // ======== P0: qm0 x qn0 — 12 reads ========
    bf16x8 a0k0[4], a0k1[4], b0k0[2], b0k1[2];
    #pragma unroll
    for (int mi = 0; mi < 4; ++mi) ds_read128(a0k0[mi], aB0 + ub + mi*2048);
    #pragma unroll
    for (int mi = 0; mi < 4; ++mi) ds_read128(a0k1[mi], aB1 + ub + mi*2048);
    #pragma unroll
    for (int ni = 0; ni < 2; ++ni) ds_read128(b0k0[ni], bB0 + ub + ni*2048);
    #pragma unroll
    for (int ni = 0; ni < 2; ++ni) ds_read128(b0k1[ni], bB1 + ub + ni*2048);
    if (notlast){
      gl_lds16(bp[0], (bf16*)(sB + 0*8192 + wave*1024)); bp[0] += 64;
      gl_lds16(bp[1], (bf16*)(sB + 1*8192 + wave*1024)); bp[1] += 64;
    }
    asm volatile("s_waitcnt lgkmcnt(8)" ::: "memory");   // queue-limit (template)
    __builtin_amdgcn_s_barrier();
    asm volatile("s_waitcnt lgkmcnt(0)" ::: "memory");
    __builtin_amdgcn_sched_barrier(0);
    __builtin_amdgcn_s_setprio(1);
    #pragma unroll
    for (int mi = 0; mi < 4; ++mi)
      #pragma unroll
      for (int ni = 0; ni < 2; ++ni)
        acc[mi][ni] = __builtin_amdgcn_mfma_f32_16x16x32_bf16(a0k0[mi], b0k0[ni], acc[mi][ni], 0, 0, 0);
    #pragma unroll
    for (int mi = 0; mi < 4; ++mi)
      #pragma unroll
      for (int ni = 0; ni < 2; ++ni)
        acc[mi][ni] = __builtin_amdgcn_mfma_f32_16x16x32_bf16(a0k1[mi], b0k1[ni], acc[mi][ni], 0, 0, 0);
    __builtin_amdgcn_s_setprio(0);
    __builtin_amdgcn_sched_barrier(0);
    __builtin_amdgcn_s_barrier();

    // ======== P1: qm0 x qn1 — 4 reads ========
    bf16x8 b1k0[2], b1k1[2];
    #pragma unroll
    for (int ni = 0; ni < 2; ++ni) ds_read128(b1k0[ni], bB0 + ub + (2+ni)*2048);
    #pragma unroll
    for (int ni = 0; ni < 2; ++ni) ds_read128(b1k1[ni], bB1 + ub + (2+ni)*2048);
    if (notlast){
      gl_lds16(bp[2], (bf16*)(sB + 2*8192 + wave*1024)); bp[2] += 64;
      gl_lds16(bp[3], (bf16*)(sB + 3*8192 + wave*1024)); bp[3] += 64;
    }
    __builtin_amdgcn_s_barrier();
    asm volatile("s_waitcnt lgkmcnt(0)" ::: "memory");
    __builtin_amdgcn_sched_barrier(0);
    __builtin_amdgcn_s_setprio(1);
    #pragma unroll
    for (int mi = 0; mi < 4; ++mi)
      #pragma unroll
      for (int ni = 0; ni < 2; ++ni)
        acc[mi][2+ni] = __builtin_amdgcn_mfma_f32_16x16x32_bf16(a0k0[mi], b1k0[ni], acc[mi][2+ni], 0, 0, 0);
    #pragma unroll
    for (int mi = 0; mi < 4; ++mi)
      #pragma unroll
      for (int ni = 0; ni < 2; ++ni)
        acc[mi][2+ni] = __builtin_amdgcn_mfma_f32_16x16x32_bf16(a0k1[mi], b1k1[ni], acc[mi][2+ni], 0, 0, 0);
    __builtin_amdgcn_s_setprio(0);
    __builtin_amdgcn_sched_barrier(0);
    if (notlast) asm volatile("s_waitcnt vmcnt(4)" ::: "memory");  // A1,A3 of t landed
    else         asm volatile("s_waitcnt vmcnt(0)" ::: "memory");
    __builtin_amdgcn_s_barrier();

    // ======== P2: qm1 x qn1 — 8 reads ========
    bf16x8 a1k0[4], a1k1[4];
    #pragma unroll
    for (int mi = 0; mi < 4; ++mi) ds_read128(a1k0[mi], aB0 + ub + (4+mi)*2048);
    #pragma unroll
    for (int mi = 0; mi < 4; ++mi) ds_read128(a1k1[mi], aB1 + ub + (4+mi)*2048);
    if (notlast){
      gl_lds16(ap[0], (bf16*)(sA + 0*8192 + wave*1024)); ap[0] += 64;
      gl_lds16(ap[2], (bf16*)(sA + 2*8192 + wave*1024)); ap[2] += 64;
    }
    __builtin_amdgcn_s_barrier();
    asm volatile("s_waitcnt lgkmcnt(0)" ::: "memory");
    __builtin_amdgcn_sched_barrier(0);
    __builtin_amdgcn_s_setprio(1);
    #pragma unroll
    for (int mi = 0; mi < 4; ++mi)
      #pragma unroll
      for (int ni = 0; ni < 2; ++ni)
        acc[4+mi][2+ni] = __builtin_amdgcn_mfma_f32_16x16x32_bf16(a1k0[mi], b1k0[ni], acc[4+mi][2+ni], 0, 0, 0);
    #pragma unroll
    for (int mi = 0; mi < 4; ++mi)
      #pragma unroll
      for (int ni = 0; ni < 2; ++ni)
        acc[4+mi][2+ni] = __builtin_amdgcn_mfma_f32_16x16x32_bf16(a1k1[mi], b1k1[ni], acc[4+mi][2+ni], 0, 0, 0);
    __builtin_amdgcn_s_setprio(0);
    __builtin_amdgcn_sched_barrier(0);
    __builtin_amdgcn_s_barrier();

    // ======== P3: qm1 x qn0 — 0 reads (a1*, b0* live) ========
    if (notlast){
      gl_lds16(ap[1], (bf16*)(sA + 1*8192 + wave*1024)); ap[1] += 64;
      gl_lds16(ap[3], (bf16*)(sA + 3*8192 + wave*1024)); ap[3] += 64;
    }
    __builtin_amdgcn_s_barrier();
    __builtin_amdgcn_sched_barrier(0);
    __builtin_amdgcn_s_setprio(1);
    #pragma unroll
    for (int mi = 0; mi < 4; ++mi)
      #pragma unroll
      for (int ni = 0; ni < 2; ++ni)
        acc[4+mi][ni] = __builtin_amdgcn_mfma_f32_16x16x32_bf16(a1k0[mi], b0k0[ni], acc[4+mi][ni], 0, 0, 0);
    #pragma unroll
    for (int mi = 0; mi < 4; ++mi)
      #pragma unroll
      for (int ni = 0; ni < 2; ++ni)
        acc[4+mi][ni] = __builtin_amdgcn_mfma_f32_16x16x32_bf16(a1k1[mi], b0k1[ni], acc[4+mi][ni], 0, 0, 0);
    __builtin_amdgcn_s_setprio(0);
    __builtin_amdgcn_sched_barrier(0);
    if (notlast) asm volatile("s_waitcnt vmcnt(2)" ::: "memory");  // next tile's P0 data landed
    __builtin_amdgcn_s_barrier();
  }

  // ---- bf16 split epilogue: 2 passes of 128 rows (stride 264 bf16)
  bf16* Cs = (bf16*)smem;
  const bool isg  = (n0 >= DI_);
  bf16* outp      = isg ? ob2 : ob;
  const int ncol0 = isg ? (n0 - DI_) : n0;
  #pragma unroll
  for (int pass = 0; pass < 2; ++pass){
    if (wm == pass){
      #pragma unroll
      for (int mi = 0; mi < 8; ++mi)
        #pragma unroll
        for (int ni = 0; ni < 4; ++ni)
          #pragma unroll
          for (int r = 0; r < 4; ++r){
            float v = acc[mi][ni][r];
            if (isg) v = silu_f(v);
            Cs[(mi*16 + quad*4 + r)*264 + wn*64 + ni*16 + l16] = (bf16)v;
          }
    }
    __syncthreads();
    #pragma unroll
    for (int it = 0; it < 8; ++it){
      const int row = it*16 + (t >> 5);
      const int c8  = (t & 31) * 8;
      bf16x8 v = *(const bf16x8*)&Cs[row*264 + c8];
      *(bf16x8*)&outp[(size_t)(m0 + pass*128 + row)*DI_ + ncol0 + c8] = v;
    }
    __syncthreads();
  }
}

// =====================================================================
// GEMM6: out = y @ out_proj_w^T (fp32 out). 256x128 tile (QN=1), BK=64,
// 8-wave, same 8-phase schedule. STANDALONE (R8, rule #19).
// Grid 32*8 = 256 blocks = full chip (256x256 gave 128 blocks, half idle).
// QN=1 ledger: prologue 6 loads, vmcnt(2) leaves A1,A3; P0 stages B0',B1'
// (4 out); P1 stages A0' (5) -> vmcnt(3) drains A1,A3 of t; P2 stages
// A2',A1' (5); P3 stages A3' (6) -> vmcnt(2). Closed invariant.
// =====================================================================
__global__ __launch_bounds__(512, 2)
void gemm256_out(const bf16* __restrict__ A, const bf16* __restrict__ W,
                 float* __restrict__ of)
{
  constexpr int MT = M_;      // 8192
  constexpr int NT = DM_;     // 1024
  constexpr int KT = DI_;     // 2048
  __shared__ __align__(16) char smem[131072];   // A: 2x32KiB | B: 2x16KiB
  char* lA = smem;
  char* lB = smem + 65536;

  const int t    = threadIdx.x;
  const int lane = t & 63;
  const int wave = t >> 6;            // 0..7
  const int wm   = wave >> 2;         // 0..1  (M half)
  const int wn   = wave & 3;          // 0..3  (N quarter)
  const int l16  = lane & 15, quad = lane >> 4;

  const int nnt = NT / 128;           // 8
  const int nwg = (MT/256) * nnt;     // 256
  const int cpx = nwg >> 3;
  int lin = (blockIdx.x & 7) * cpx + (blockIdx.x >> 3);
  const int m0 = (lin / nnt) * 256;
  const int n0 = (lin % nnt) * 128;

  const int r8     = lane >> 3;
  const int lchunk = (lane & 7) ^ r8;
  const bf16* ap[4]; const bf16* bp[2];
  #pragma unroll
  for (int s = 0; s < 4; ++s)
    ap[s] = A + (size_t)(m0 + s*64 + wave*8 + r8) * KT + lchunk*8;
  #pragma unroll
  for (int s = 0; s < 2; ++s)
    bp[s] = W + (size_t)(n0 + s*64 + wave*8 + r8) * KT + lchunk*8;

  const uint32_t lAu = (uint32_t)(uintptr_t)(__attribute__((address_space(3))) char*)lA;
  const uint32_t lBu = (uint32_t)(uintptr_t)(__attribute__((address_space(3))) char*)lB;
  const uint32_t swz0 = (uint32_t)(((quad    ) ^ (l16 & 7)) << 4);
  const uint32_t swz1 = (uint32_t)(((4 | quad) ^ (l16 & 7)) << 4);
  const uint32_t aB0 = lAu + (uint32_t)((wm*128 + l16) * 128) + swz0;
  const uint32_t aB1 = lAu + (uint32_t)((wm*128 + l16) * 128) + swz1;
  const uint32_t bB0 = lBu + (uint32_t)((wn*32 + l16) * 128) + swz0;
  const uint32_t bB1 = lBu + (uint32_t)((wn*32 + l16) * 128) + swz1;

  f32x4 acc[8][2] = {};
  constexpr int NTILES = KT / 64;     // 32

  gl_lds16(bp[0], (bf16*)(lB + 0*8192 + wave*1024)); bp[0] += 64;
  gl_lds16(bp[1], (bf16*)(lB + 1*8192 + wave*1024)); bp[1] += 64;
  gl_lds16(ap[0], (bf16*)(lA + 0*8192 + wave*1024)); ap[0] += 64;
  gl_lds16(ap[2], (bf16*)(lA + 2*8192 + wave*1024)); ap[2] += 64;
  gl_lds16(ap[1], (bf16*)(lA + 1*8192 + wave*1024)); ap[1] += 64;
  gl_lds16(ap[3], (bf16*)(lA + 3*8192 + wave*1024)); ap[3] += 64;
  asm volatile("s_waitcnt vmcnt(2)" ::: "memory");   // all but A1,A3 landed
  __builtin_amdgcn_s_barrier();

  for (int tt = 0; tt < NTILES; ++tt){
    const int u = tt & 1;
    const uint32_t ub = (uint32_t)(u << 15);
    char* sA = lA + (u^1)*32768;
    char* sB = lB + (u^1)*32768;
    const bool notlast = (tt + 1 < NTILES);

    // ======== P0: qm0 x qn0 — 10 reads ========
    bf16x8 a0k0[4], a0k1[4], b0k0[1], b0k1[1];
    #pragma unroll
    for (int mi = 0; mi < 4; ++mi) ds_read128(a0k0[mi], aB0 + ub + mi*2048);
    #pragma unroll
    for (int mi = 0; mi < 4; ++mi) ds_read128(a0k1[mi], aB1 + ub + mi*2048);
    ds_read128(b0k0[0], bB0 + ub);
    ds_read128(b0k1[0], bB1 + ub);
    if (notlast){
      gl_lds16(bp[0], (bf16*)(sB + 0*8192 + wave*1024)); bp[0] += 64;
      gl_lds16(bp[1], (bf16*)(sB + 1*8192 + wave*1024)); bp[1] += 64;
    }
    __builtin_amdgcn_s_barrier();
    asm volatile("s_waitcnt lgkmcnt(0)" ::: "memory");
    __builtin_amdgcn_sched_barrier(0);
    __builtin_amdgcn_s_setprio(1);
    #pragma unroll
    for (int mi = 0; mi < 4; ++mi)
      acc[mi][0] = __builtin_amdgcn_mfma_f32_16x16x32_bf16(a0k0[mi], b0k0[0], acc[mi][0], 0, 0, 0);
    #pragma unroll
    for (int mi = 0; mi < 4; ++mi)
      acc[mi][0] = __builtin_amdgcn_mfma_f32_16x16x32_bf16(a0k1[mi], b0k1[0], acc[mi][0], 0, 0, 0);
    __builtin_amdgcn_s_setprio(0);
    __builtin_amdgcn_sched_barrier(0);
    __builtin_amdgcn_s_barrier();

    // ======== P1: qm0 x qn1 — 2 reads ========
    bf16x8 b1k0[1], b1k1[1];
    ds_read128(b1k0[0], bB0 + ub + 2048);
    ds_read128(b1k1[0], bB1 + ub + 2048);
    if (notlast){
      gl_lds16(ap[0], (bf16*)(sA + 0*8192 + wave*1024)); ap[0] += 64;
    }
    __builtin_amdgcn_s_barrier();
    asm volatile("s_waitcnt lgkmcnt(0)" ::: "memory");
    __builtin_amdgcn_sched_barrier(0);
    __builtin_amdgcn_s_setprio(1);
    #pragma unroll
    for (int mi = 0; mi < 4; ++mi)
      acc[mi][1] = __builtin_amdgcn_mfma_f32_16x16x32_bf16(a0k0[mi], b1k0[0], acc[mi][1], 0, 0, 0);
    #pragma unroll
    for (int mi = 0; mi < 4; ++mi)
      acc[mi][1] = __builtin_amdgcn_mfma_f32_16x16x32_bf16(a0k1[mi], b1k1[0], acc[mi][1], 0, 0, 0);
    __builtin_amdgcn_s_setprio(0);
    __builtin_amdgcn_sched_barrier(0);
    if (notlast) asm volatile("s_waitcnt vmcnt(3)" ::: "memory");  // A1,A3 of t landed
    else         asm volatile("s_waitcnt vmcnt(0)" ::: "memory");
    __builtin_amdgcn_s_barrier();

    // ======== P2: qm1 x qn1 — 8 reads ========
    bf16x8 a1k0[4], a1k1[4];
    #pragma unroll
    for (int mi = 0; mi < 4; ++mi) ds_read128(a1k0[mi], aB0 + ub + (4+mi)*2048);
    #pragma unroll
    for (int mi = 0; mi < 4; ++mi) ds_read128(a1k1[mi], aB1 + ub + (4+mi)*2048);
    if (notlast){
      gl_lds16(ap[2], (bf16*)(sA + 2*8192 + wave*1024)); ap[2] += 64;
      gl_lds16(ap[1], (bf16*)(sA + 1*8192 + wave*1024)); ap[1] += 64;
    }
    __builtin_amdgcn_s_barrier();
    asm volatile("s_waitcnt lgkmcnt(0)" ::: "memory");
    __builtin_amdgcn_sched_barrier(0);
    __builtin_amdgcn_s_setprio(1);
    #pragma unroll
    for (int mi = 0; mi < 4; ++mi)
      acc[4+mi][1] = __builtin_amdgcn_mfma_f32_16x16x32_bf16(a1k0[mi], b1k0[0], acc[4+mi][1], 0, 0, 0);
    #pragma unroll
    for (int mi = 0; mi < 4; ++mi)
      acc[4+mi][1] = __builtin_amdgcn_mfma_f32_16x16x32_bf16(a1k1[mi], b1k1[0], acc[4+mi][1], 0, 0, 0);
    __builtin_amdgcn_s_setprio(0);
    __builtin_amdgcn_sched_barrier(0);
    __builtin_amdgcn_s_barrier();

    // ======== P3: qm1 x qn0 — 0 reads ========
    if (notlast){
      gl_lds16(ap[3], (bf16*)(sA + 3*8192 + wave*1024)); ap[3] += 64;
    }
    __builtin_amdgcn_s_barrier();
    __builtin_amdgcn_sched_barrier(0);
    __builtin_amdgcn_s_setprio(1);
    #pragma unroll
    for (int mi = 0; mi < 4; ++mi)
      acc[4+mi][0] = __builtin_amdgcn_mfma_f32_16x16x32_bf16(a1k0[mi], b0k0[0], acc[4+mi][0], 0, 0, 0);
    #pragma unroll
    for (int mi = 0; mi < 4; ++mi)
      acc[4+mi][0] = __builtin_amdgcn_mfma_f32_16x16x32_bf16(a1k1[mi], b0k1[0], acc[4+mi][0], 0, 0, 0);
    __builtin_amdgcn_s_setprio(0);
    __builtin_amdgcn_sched_barrier(0);
    if (notlast) asm volatile("s_waitcnt vmcnt(2)" ::: "memory");  // next tile's P0 data landed
    __builtin_amdgcn_s_barrier();
  }

  // ---- fp32 epilogue: 4 passes of 64 rows through LDS (stride 132 f32)
  float* Cf = (float*)smem;
  #pragma unroll
  for (int pass = 0; pass < 4; ++pass){
    if (wm == (pass >> 1)){
      #pragma unroll
      for (int mi2 = 0; mi2 < 4; ++mi2){
        const int mi = (pass & 1)*4 + mi2;
        #pragma unroll
        for (int ni = 0; ni < 2; ++ni)
          #pragma unroll
          for (int r = 0; r < 4; ++r)
            Cf[(mi2*16 + quad*4 + r)*132 + wn*32 + ni*16 + l16] = acc[mi][ni][r];
      }
    }
    __syncthreads();
    #pragma unroll
    for (int it = 0; it < 4; ++it){
      const int row = it*16 + (t >> 5);
      const int c4  = (t & 31) * 4;
      float4 v = *(const float4*)&Cf[row*132 + c4];
      *(float4*)&of[(size_t)(m0 + pass*64 + row)*NT + n0 + c4] = v;
    }
    __syncthreads();
  }
}

// ---------------- GEMM: C[M,N] = A[M,K] * W[N,K]^T, bf16 MFMA ----------------
// m97 K-loop, 128-tile path for the small/odd-shape GEMMs.
// EPI: 2 = dt epilogue (softplus/clip -> delta bf16) + FUSED scan pass1
//      4 = split-K partial fp32 (dt_low, N=64), K-slice from blockIdx.z
template<int EPI, int MT, int NT, int KT>
__global__ __launch_bounds__(256)
void gemm_bt(const bf16* __restrict__ A, const bf16* __restrict__ W,
             float* __restrict__ o0, bf16* __restrict__ ob, bf16* __restrict__ ob2,
             const float* __restrict__ bias, const float* __restrict__ alog,
             const bf16* __restrict__ uq, float* __restrict__ Pq,
             float* __restrict__ Fq)
{
  __shared__ char smem[34816];                 // As/Bs (16 KiB) reused as C-stage
  bf16* As = (bf16*)smem;
  bf16* Bs = (bf16*)(smem + 128*BK_*2);
  const int t    = threadIdx.x;
  const int lane = t & 63;
  const int wave = t >> 6;
  const int wm   = wave >> 1, wn = wave & 1;
  const int l16  = lane & 15, quad = lane >> 4;

  int m0, n0;
  if (EPI == 4){
    m0 = blockIdx.y * 128; n0 = 0;
  } else {
    const int gx  = NT / 128;
    const int lin = blockIdx.y * gx + blockIdx.x;
    const int grp = lin / (gx * 4);
    const int rem = lin % (gx * 4);
    m0 = (grp * 4 + (rem & 3)) * 128;
    n0 = (rem >> 2) * 128;
  }

  const int srow = (lane >> 2);
  const int scol = (lane & 3) * 8;

  const int KFULL = (EPI == 4) ? (KT * KSPL) : KT;
  const int kbase = (EPI == 4) ? (int)blockIdx.z * KT : 0;

  const int rowA0 = m0 + wave*32 + srow;
  int rB0 = n0 + wave*32 + srow, rB1 = rB0 + 16;
  if (NT < 128){ rB0 = (rB0 >= NT) ? NT-1 : rB0; rB1 = (rB1 >= NT) ? NT-1 : rB1; }
  const bf16* ap0 = A + (size_t)rowA0*KFULL        + kbase + scol;
  const bf16* ap1 = A + (size_t)(rowA0+16)*KFULL   + kbase + scol;
  const bf16* bp0 = W + (size_t)rB0*KFULL          + kbase + scol;
  const bf16* bp1 = W + (size_t)rB1*KFULL          + kbase + scol;
  bf16* lA0 = &As[(wave*32)*BK_];
  bf16* lA1 = &As[(wave*32+16)*BK_];
  bf16* lB0 = &Bs[(wave*32)*BK_];
  bf16* lB1 = &Bs[(wave*32+16)*BK_];

  f32x4 acc[4][4] = {};
  constexpr int kframes = KT / BK_;

  for (int kt = 0; kt < kframes; ++kt){
    gl_lds16(ap0, lA0);  gl_lds16(ap1, lA1);
    gl_lds16(bp0, lB0);  gl_lds16(bp1, lB1);
    ap0 += BK_; ap1 += BK_; bp0 += BK_; bp1 += BK_;
    __syncthreads();
    bf16x8 af[4], bf_[4];
    #pragma unroll
    for (int i = 0; i < 4; ++i){
      af[i]  = *(const bf16x8*)&As[(wm*64 + i*16 + l16)*BK_ + quad*8];
      bf_[i] = *(const bf16x8*)&Bs[(wn*64 + i*16 + l16)*BK_ + quad*8];
    }
    #pragma unroll
    for (int mi = 0; mi < 4; ++mi)
      #pragma unroll
      for (int ni = 0; ni < 4; ++ni)
        acc[mi][ni] = __builtin_amdgcn_mfma_f32_16x16x32_bf16(af[mi], bf_[ni], acc[mi][ni], 0, 0, 0);
    __syncthreads();
  }

  if (EPI == 4){
    float* Cf = (float*)smem;
    if (wn == 0){
      #pragma unroll
      for (int mi = 0; mi < 4; ++mi)
        #pragma unroll
        for (int ni = 0; ni < 4; ++ni)
          #pragma unroll
          for (int r = 0; r < 4; ++r)
            Cf[(wm*64 + mi*16 + quad*4 + r)*LDCF + ni*16 + l16] = acc[mi][ni][r];
    }
    __syncthreads();
    #pragma unroll
    for (int it = 0; it < 8; ++it){
      const int row = it*16 + (t >> 4);
      const int c4  = (t & 15) * 4;
      float4 v = *(const float4*)&Cf[row*LDCF + c4];
      *(float4*)&o0[((size_t)blockIdx.z*M_ + m0 + row)*DT_ + c4] = v;
    }
  } else {
    // bf16 outputs (EPI 2) via padded LDS stage
    bf16* Cs = (bf16*)smem;
    #pragma unroll
    for (int mi = 0; mi < 4; ++mi){
      #pragma unroll
      for (int ni = 0; ni < 4; ++ni){
        const int n = n0 + wn*64 + ni*16 + l16;
        #pragma unroll
        for (int r = 0; r < 4; ++r){
          float v = acc[mi][ni][r];
          v = softplus_f(v + bias[n]);
          v = fminf(fmaxf(v, 1e-6f), 10.f);      // delta
          Cs[(wm*64 + mi*16 + quad*4 + r)*LDC + wn*64 + ni*16 + l16] = (bf16)v;
        }
      }
    }
    __syncthreads();
    #pragma unroll
    for (int it = 0; it < 8; ++it){
      const int row = it*16 + (t >> 4);
      const int c8  = (t & 15) * 8;
      bf16x8 v = *(const bf16x8*)&Cs[row*LDC + c8];
      *(bf16x8*)&ob[(size_t)(m0+row)*NT + n0 + c8] = v;
    }
    {
      // fused scan pass1 (bit-identical to standalone: uses bf16 delta in LDS)
      const int chunk = t >> 7;
      const int dcol  = t & 127;
      const int dglob = n0 + dcol;
      const float Ad  = a_of(alog, dglob);
      const int b  = m0 >> 12;
      const int c0 = (m0 & 4095) >> 6;
      const size_t ubase = (size_t)(m0 + chunk*64)*DI_ + dglob;
      float p = 1.f, f = 0.f;
      for (int i = 0; i < CH_; ++i){
        float dl = (float)Cs[(chunk*64 + i)*LDC + dcol];
        float ee = e_of(dl, Ad);
        float uu = (float)uq[ubase + (size_t)i*DI_];
        f = f*ee + uu;
        p *= ee;
      }
      const size_t o = ((size_t)(b*G_ + c0 + chunk))*DI_ + dglob;
      Pq[o] = p; Fq[o] = f;
    }
  }
}

// ---------------- split-K reduce: dtl = sum_z partial[z] (bf16) ----------------
// Vectorized — float4 loads (16 B/lane), 4 outputs/thread, bf16x4 store.
__global__ __launch_bounds__(256)
void dt_reduce_kernel(const float* __restrict__ part, bf16* __restrict__ dtl){
  const int i = (blockIdx.x*256 + threadIdx.x) * 4;   // m*DT + n, x4
  float4 s = *(const float4*)&part[i];
  #pragma unroll
  for (int z = 1; z < KSPL; ++z){
    float4 v = *(const float4*)&part[(size_t)z*M_*DT_ + i];
    s.x += v.x; s.y += v.y; s.z += v.z; s.w += v.w;
  }
  bf16x4 o = {(bf16)s.x, (bf16)s.y, (bf16)s.z, (bf16)s.w};
  *(bf16x4*)&dtl[i] = o;
}

// ---------------- depthwise causal conv (K=4) + bias + SiLU ----------------
// Vectorized bf16x8 (G13) — one block = one (b,l) row, lane owns 8 d's.
__global__ __launch_bounds__(256)
void conv_silu_kernel(const bf16* __restrict__ xi, const float* __restrict__ cw,
                      const float* __restrict__ cb, bf16* __restrict__ ubf)
{
  const int row = blockIdx.x;               // b*L + l
  const int l   = row & (L_-1);
  const int d0  = threadIdx.x * 8;
  const size_t base = (size_t)row*DI_ + d0;
  float s[8];
  #pragma unroll
  for (int j = 0; j < 8; ++j) s[j] = cb[d0+j];
  float w[8][4];
  #pragma unroll
  for (int j = 0; j < 8; ++j){
    float4 wv = *(const float4*)&cw[(d0+j)*4];
    w[j][0] = wv.x; w[j][1] = wv.y; w[j][2] = wv.z; w[j][3] = wv.w;
  }
  #pragma unroll
  for (int k = 0; k < 4; ++k){
    const int ll = l + k - 3;
    if (ll >= 0){
      bf16x8 xv = *(const bf16x8*)&xi[base + (ptrdiff_t)(k-3)*DI_];
      #pragma unroll
      for (int j = 0; j < 8; ++j) s[j] += (float)xv[j] * w[j][k];
    }
  }
  bf16x8 o;
  #pragma unroll
  for (int j = 0; j < 8; ++j) o[j] = (bf16)silu_f(s[j]);
  *(bf16x8*)&ubf[base] = o;
}

// ---------------- scan pass3 (with inlined pass2 prefix) ----------------
// R8: reverted to scalar 1024-block form — R7's 4-d/thread variant dropped
// occupancy to 1 block/CU (4 waves) and regressed this latency-bound kernel.
__global__ __launch_bounds__(256)
void scan_pass3(const bf16* __restrict__ delta, const bf16* __restrict__ u,
                const bf16* __restrict__ g, const float* __restrict__ P,
                const float* __restrict__ F, const float* __restrict__ alog,
                const float* __restrict__ Dp, bf16* __restrict__ y)
{
  const int d = blockIdx.x*256 + threadIdx.x;
  const int c = blockIdx.y, b = blockIdx.z;
  const float Ad = a_of(alog, d);
  float s = 0.f;
  for (int cc = 0; cc < c; ++cc){
    const size_t o = ((size_t)(b*G_ + cc))*DI_ + d;
    s = F[o] + P[o]*s;
  }
  size_t base = ((size_t)(b*L_ + c*CH_))*DI_ + d;
  const float Dd = Dp[d];
  for (int i = 0; i < CH_; ++i){
    const size_t idx = base + (size_t)i*DI_;
    const float uu = (float)u[idx];
    s = s*e_of((float)delta[idx], Ad) + uu;
    float yy = s + uu*Dd;
    yy = fminf(fmaxf(yy, -1e4f), 1e4f);
    yy *= (float)g[idx];              // g = silu(z), from GEMM1 epilogue
    y[idx] = (bf16)yy;
  }
}

// ---------------- host launch ----------------
extern "C" void kernel_launch(void* const* d_in, const int* in_sizes, int n_in,
                              void* d_out, int out_size, void* d_ws, size_t ws_size,
                              hipStream_t stream)
{
  (void)in_sizes; (void)n_in; (void)out_size; (void)ws_size;
  const float* x        = (const float*)d_in[0];
  const float* in_w     = (const float*)d_in[1];
  const float* conv_w   = (const float*)d_in[2];
  const float* conv_b   = (const float*)d_in[3];
  const float* xproj_w  = (const float*)d_in[4];
  const float* dtproj_w = (const float*)d_in[5];
  const float* dtproj_b = (const float*)d_in[6];
  const float* A_log    = (const float*)d_in[7];
  const float* Dp       = (const float*)d_in[8];
  const float* out_w    = (const float*)d_in[9];

  char* base = (char*)d_ws;
  const size_t MiB = 1024*1024;
  bf16*  xi_bf = (bf16*) (base + 0);
  float* part  = (float*)(base + 0);          // 16 MiB
  bf16*  dl_bf = (bf16*) (base + 0);          // delta, 32 MiB
  bf16*  x_bf  = (bf16*) (base + 32*MiB);     // 16 MiB
  bf16*  w1_bf = (bf16*) (base + 48*MiB);     // 8 MiB
  bf16*  g_bf  = (bf16*) (base + 64*MiB);     // 32 MiB
  bf16*  u_bf  = (bf16*) (base + 96*MiB);     // 32 MiB
  bf16*  y_bf  = (bf16*) (base + 128*MiB);    // 32 MiB
  bf16*  wo_bf = (bf16*) (base + 160*MiB);    // 4 MiB
  bf16*  xp_bf = (bf16*) (base + 164*MiB);    // 0.25 MiB
  bf16*  dp_bf = (bf16*) (base + 165*MiB);    // 0.25 MiB
  bf16*  dtl_bf= (bf16*) (base + 166*MiB);    // 1 MiB
  float* P     = (float*)(base + 167*MiB);    // 1 MiB
  float* F     = (float*)(base + 168*MiB);    // 1 MiB

  const int c0 = (M_*DM_)/4, c1 = (2*DI_*DM_)/4, c2 = (DT_*DI_)/4,
            c3 = (DI_*DT_)/4, c4 = (DM_*DI_)/4;
  const int ctot = c0+c1+c2+c3+c4;
  cvt_all_kernel<<<(ctot+255)/256, 256, 0, stream>>>(
      (const float4*)x,        (bf16x4*)x_bf,  c0,
      (const float4*)in_w,     (bf16x4*)w1_bf, c1,
      (const float4*)xproj_w,  (bf16x4*)xp_bf, c2,
      (const float4*)dtproj_w, (bf16x4*)dp_bf, c3,
      (const float4*)out_w,    (bf16x4*)wo_bf, c4);

  // 1) xz = x @ in_proj_w^T ; split -> xi (bf16), g=silu(z) (bf16)
  //    standalone 256^2 8-phase kernel; grid 32*16=512 (%8==0)
  gemm256_xz<<<dim3(512), 512, 0, stream>>>(x_bf, w1_bf, xi_bf, g_bf);
  // 2) depthwise causal conv + bias + silu -> u (bf16); 1 block per (b,l) row
  conv_silu_kernel<<<M_, 256, 0, stream>>>(xi_bf, conv_w, conv_b, u_bf);
  // 3) dt_low = u @ x_proj_w^T, split-K=8 -> fp32 partials
  gemm_bt<4, M_, DT_, KSL><<<dim3(1, M_/128, KSPL), 256, 0, stream>>>(
      u_bf, xp_bf, part, nullptr, nullptr, nullptr,
      nullptr, nullptr, nullptr, nullptr);
  dt_reduce_kernel<<<(M_*DT_)/1024, 256, 0, stream>>>(part, dtl_bf);
  // 4) delta = clip(softplus(dtl @ dt_proj_w^T + b)) -> bf16 + fused scan pass1
  gemm_bt<2, M_, DI_, DT_><<<dim3(DI_/128, M_/128), 256, 0, stream>>>(
      dtl_bf, dp_bf, nullptr, dl_bf, nullptr, dtproj_b,
      A_log, u_bf, P, F);
  // 5) scan: prefix from P,F + within-chunk states + skip + gate -> y (bf16)
  scan_pass3<<<dim3(DI_/256, G_, B_), 256, 0, stream>>>(
      dl_bf, u_bf, g_bf, P, F, A_log, Dp, y_bf);
  // 6) out = y @ out_proj_w^T (fp32) — standalone 256x128 kernel, 256 blocks
  gemm256_out<<<dim3(256), 512, 0, stream>>>(y_bf, wo_bf, (float*)d_out);
}